// Round 1
// 548.088 us; speedup vs baseline: 1.3360x; 1.3360x over previous
//
#include <hip/hip_runtime.h>
#include <hip/hip_bf16.h>

// LSTMblock: 2-layer, 8-head LSTM (H=F=64, T=12) over N=16384 nodes, then
// 1x1 conv mixing (head,t) channels (96 -> 12). fp32 I/O, bf16 MFMA, fp32 cell.
//
// R5: counters showed neither pipe busy (Mfma 15.6%, HBM 13.5%, VALU 44.6%)
// with 84 VGPR under a 170-reg cap while the working set needs ~200 regs ->
// weights were being re-materialized from global inside every one of the 25
// barrier phases, and each phase's pre-barrier vmcnt(0) drained them.
// Restructure: 512-thread blocks, waves split BY LAYER (w0-3: layer0 tiles,
// w4-7: layer1 tiles), software-pipelined l0[t] || l1[t-1]. Each wave holds
// only its layer's weights (64 regs) -> fully resident at 128-reg/4-wave
// budget; barriers 25 -> 14; bias folded into MFMA C-init. One-time prep
// kernels pre-convert x + weights to bf16 (kills per-block cvt storm).
// conv kernel: unroll 8 (8 loads in flight) + 2 elems/thread (2048 blocks).
//
// MFMA v_mfma_f32_16x16x32_bf16 lane mapping (m89/m120-verified):
//   A[m][k]: lane(quad,col) reg j holds A[m=col][k=quad*8+j]
//   B[k][n]: lane reg j holds B[k=quad*8+j][n=col]
//   D[m][n]: lane reg r holds D[m=quad*4+r][n=col]

#define T_LEN 12
#define NHEADS 8
#define HD 64
#define NNODES 16384
#define MT 16
#define LDSP 72
#define WIH_ELEMS (2 * NHEADS * 4 * HD * HD)   // 262144 elems per weight tensor

typedef __bf16 bf16_t;
typedef __attribute__((ext_vector_type(2))) __bf16 bf16x2;
typedef __attribute__((ext_vector_type(4))) __bf16 bf16x4;
typedef __attribute__((ext_vector_type(8))) __bf16 bf16x8;
typedef __attribute__((ext_vector_type(2))) float f32x2;
typedef __attribute__((ext_vector_type(4))) float f32x4;

#define MFMA16(a, b, c) __builtin_amdgcn_mfma_f32_16x16x32_bf16((a), (b), (c), 0, 0, 0)

__device__ __forceinline__ float fast_sigmoid(float v) {
    return __builtin_amdgcn_rcpf(1.0f + __expf(-v));
}
__device__ __forceinline__ float fast_tanh(float v) {
    return 2.0f * __builtin_amdgcn_rcpf(1.0f + __expf(-2.0f * v)) - 1.0f;
}

__device__ __forceinline__ bf16x8 load8f(const float* p) {
    f32x4 a = *(const f32x4*)p;
    f32x4 b = *(const f32x4*)(p + 4);
    bf16x8 r;
    r[0] = (bf16_t)a[0]; r[1] = (bf16_t)a[1]; r[2] = (bf16_t)a[2]; r[3] = (bf16_t)a[3];
    r[4] = (bf16_t)b[0]; r[5] = (bf16_t)b[1]; r[6] = (bf16_t)b[2]; r[7] = (bf16_t)b[3];
    return r;
}
__device__ __forceinline__ bf16x4 load4f(const float* p) {
    f32x4 a = *(const f32x4*)p;
    bf16x4 r;
    r[0] = (bf16_t)a[0]; r[1] = (bf16_t)a[1]; r[2] = (bf16_t)a[2]; r[3] = (bf16_t)a[3];
    return r;
}

// Batched LSTM gate pointwise: one v_rcp serves 4 denominators. Inputs are
// PRE-BIASED gate pre-activations (bias folded into MFMA C-init).
struct Gates { float sig_i, sig_f, tanh_g, sig_o; };
__device__ __forceinline__ Gates gate_eval(float gi, float gf, float gg, float go) {
    float ei = __expf(-gi), ef = __expf(-gf), eg = __expf(-2.0f * gg), eo = __expf(-go);
    float di = 1.0f + ei, df = 1.0f + ef, dg = 1.0f + eg, do_ = 1.0f + eo;
    float pif = di * df, pgo = dg * do_;
    float rr  = __builtin_amdgcn_rcpf(pif * pgo);
    float rif = rr * pgo, rgo = rr * pif;
    Gates g;
    g.sig_i  = rif * df;
    g.sig_f  = rif * di;
    g.tanh_g = 2.0f * (rgo * do_) - 1.0f;
    g.sig_o  = rgo * dg;
    return g;
}

// 4-way batched tanh with one shared rcp.
__device__ __forceinline__ void tanh4(const float x[4], float out[4]) {
    float d0 = 1.0f + __expf(-2.0f * x[0]);
    float d1 = 1.0f + __expf(-2.0f * x[1]);
    float d2 = 1.0f + __expf(-2.0f * x[2]);
    float d3 = 1.0f + __expf(-2.0f * x[3]);
    float p01 = d0 * d1, p23 = d2 * d3;
    float rr  = __builtin_amdgcn_rcpf(p01 * p23);
    float r01 = rr * p23, r23 = rr * p01;
    out[0] = 2.0f * (r01 * d1) - 1.0f;
    out[1] = 2.0f * (r01 * d0) - 1.0f;
    out[2] = 2.0f * (r23 * d3) - 1.0f;
    out[3] = 2.0f * (r23 * d2) - 1.0f;
}

// Gate pointwise for one wave's 4 rows; updates cell regs, writes h to LDS.
__device__ __forceinline__ void lstm_pointwise(const f32x4* acc, float* creg,
                                               bf16_t* D, int quad, int wq, int col) {
    float cn[4], so[4], tc[4];
    #pragma unroll
    for (int r = 0; r < 4; ++r) {
        Gates g = gate_eval(acc[0][r], acc[1][r], acc[2][r], acc[3][r]);
        cn[r] = g.sig_f * creg[r] + g.sig_i * g.tanh_g;
        so[r] = g.sig_o;
        creg[r] = cn[r];
    }
    tanh4(cn, tc);
    #pragma unroll
    for (int r = 0; r < 4; ++r)
        D[(quad * 4 + r) * LDSP + wq * 16 + col] = (bf16_t)(so[r] * tc[r]);
}

// ============== prep: fp32 -> bf16 bulk convert (x, Wih, Whh) ==============
__global__ __launch_bounds__(256) void cvt_bf16_kernel(
    const float* __restrict__ src, bf16_t* __restrict__ dst, int n8)
{
    int i = blockIdx.x * 256 + threadIdx.x;
    if (i < n8) *(bf16x8*)(dst + (size_t)i * 8) = load8f(src + (size_t)i * 8);
}

// ====== kernel 1: per-(tile,head) 2-layer LSTM, layer-split waves ======
// 512 threads: waves 0-3 compute layer0 gate n-tiles, waves 4-7 layer1.
// Pipeline: phase p computes l0[t=p] and l1[t=p-1]; both read h_l0[p-1]
// from the same LDS buffer. One barrier per phase (13 phases + staging).
template<bool PREP>
__global__ __launch_bounds__(512, 4) void lstm_pipe_kernel(
    const float* __restrict__ xg,   // (T, N, 64) fp32
    const bf16_t* __restrict__ xbf, // (T, N, 64) bf16 (PREP)
    const float* __restrict__ Wih,  // (2, 8, 256, 64)
    const float* __restrict__ Whh,  // (2, 8, 256, 64)
    const bf16_t* __restrict__ wbf, // [Wih | Whh] bf16 (PREP)
    const float* __restrict__ bih,  // (2, 8, 256)
    const float* __restrict__ bhh,  // (2, 8, 256)
    const float* __restrict__ h0g,  // (8, 2, N, 64)
    const float* __restrict__ c0g,  // (8, 2, N, 64)
    bf16_t* __restrict__ hsw)       // (96, N, 64) channel-major hs
{
    __shared__ __align__(16) bf16_t xT[T_LEN][MT][LDSP];   // x tile, A-layout
    __shared__ __align__(16) bf16_t h0A[2][MT][LDSP];      // layer0 h, dbuf
    __shared__ __align__(16) bf16_t h1A[2][MT][LDSP];      // layer1 h, dbuf

    const int tid  = threadIdx.x;
    const int w    = tid >> 6;
    const int lane = tid & 63;
    const int quad = lane >> 4;
    const int col  = lane & 15;
    const int lw   = w >> 2;        // layer this wave serves (0 or 1)
    const int wq   = w & 3;         // gate n-tile group within the layer
    const int a    = blockIdx.x & (NHEADS - 1);
    const int nb   = (blockIdx.x >> 3) * MT;

    // ---- x tile -> LDS (once per block) ----
    #pragma unroll
    for (int it = 0; it < 3; ++it) {
        int e    = (it * 512 + tid) * 8;
        int t    = e >> 10;
        int node = (e >> 6) & (MT - 1);
        int f    = e & (HD - 1);
        bf16x8 v;
        if (PREP) v = *(const bf16x8*)(xbf + ((size_t)t * NNODES + nb + node) * HD + f);
        else      v = load8f(xg + ((size_t)t * NNODES + nb + node) * HD + f);
        *(bf16x8*)&xT[t][node][f] = v;
    }
    // ---- h0 init: layer0 -> h0A[0], layer1 -> h1A[1] (parity: l1 first reads at p=1) ----
    {
        int e    = tid * 4;
        int l    = e >> 10;
        int node = (e >> 6) & (MT - 1);
        int hh   = e & (HD - 1);
        bf16x4 v = load4f(h0g + (((size_t)a * 2 + l) * NNODES + nb + node) * HD + hh);
        if (l == 0) *(bf16x4*)&h0A[0][node][hh] = v;
        else        *(bf16x4*)&h1A[1][node][hh] = v;
    }

    // ---- this wave's layer weights, register-resident (64 regs) ----
    bf16x8 wA[4][2], wB[4][2];      // [gate i/f/g/o][kfrag]; A=W_ih, B=W_hh
    #pragma unroll
    for (int ni = 0; ni < 4; ++ni)
        #pragma unroll
        for (int kf = 0; kf < 2; ++kf) {
            size_t off = (((size_t)lw * NHEADS + a) * 256 + (4 * ni + wq) * 16 + col) * HD
                       + kf * 32 + quad * 8;
            if (PREP) {
                wA[ni][kf] = *(const bf16x8*)(wbf + off);
                wB[ni][kf] = *(const bf16x8*)(wbf + WIH_ELEMS + off);
            } else {
                wA[ni][kf] = load8f(Wih + off);
                wB[ni][kf] = load8f(Whh + off);
            }
        }
    float bias[4];
    #pragma unroll
    for (int ni = 0; ni < 4; ++ni) {
        int off = (lw * NHEADS + a) * 256 + ni * 64 + wq * 16 + col;
        bias[ni] = bih[off] + bhh[off];
    }
    float creg[4];
    #pragma unroll
    for (int r = 0; r < 4; ++r)
        creg[r] = c0g[(((size_t)a * 2 + lw) * NNODES + nb + quad * 4 + r) * HD
                      + wq * 16 + col];
    __syncthreads();

    int cur = 0;
    #pragma unroll 1
    for (int p = 0; p <= T_LEN; ++p) {
        // hs store for t=p-2 (written into h1A[cur] last phase); issued early
        // so the store is ~a full phase ahead of the pre-barrier vm drain.
        if (p >= 2) {
            int node = tid >> 5;
            int h2   = (tid & 31) * 2;
            *(bf16x2*)(hsw + ((size_t)(a * T_LEN + p - 2) * NNODES + nb + node) * HD + h2) =
                *(const bf16x2*)&h1A[cur][node][h2];
        }
        const bool active = lw ? (p >= 1) : (p < T_LEN);
        if (active) {
            // l0: gates = x[p]*Wih0 + h_l0[p-1]*Whh0
            // l1: gates = h_l0[p-1]*Wih1 + h_l1[p-2]*Whh1
            const bf16_t* P = lw ? &h0A[cur][0][0] : &xT[p][0][0];
            const bf16_t* Q = lw ? &h1A[cur][0][0] : &h0A[cur][0][0];
            bf16_t*       D = lw ? &h1A[cur ^ 1][0][0] : &h0A[cur ^ 1][0][0];
            const int ro = col * LDSP + quad * 8;
            bf16x8 a0 = *(const bf16x8*)(P + ro);
            bf16x8 b0 = *(const bf16x8*)(Q + ro);
            f32x4 acc[4];
            #pragma unroll
            for (int ni = 0; ni < 4; ++ni) {
                f32x4 z = {bias[ni], bias[ni], bias[ni], bias[ni]};  // bias as C-init
                z = MFMA16(a0, wA[ni][0], z);
                acc[ni] = MFMA16(b0, wB[ni][0], z);
            }
            bf16x8 a1 = *(const bf16x8*)(P + ro + 32);
            bf16x8 b1 = *(const bf16x8*)(Q + ro + 32);
            #pragma unroll
            for (int ni = 0; ni < 4; ++ni) {
                f32x4 z = MFMA16(a1, wA[ni][1], acc[ni]);
                acc[ni] = MFMA16(b1, wB[ni][1], z);
            }
            lstm_pointwise(acc, creg, D, quad, wq, col);
        }
        __syncthreads();
        cur ^= 1;
    }
    // final hs store (t = 11)
    {
        int node = tid >> 5;
        int h2   = (tid & 31) * 2;
        *(bf16x2*)(hsw + ((size_t)(a * T_LEN + 11) * NNODES + nb + node) * HD + h2) =
            *(const bf16x2*)&h1A[cur][node][h2];
    }
}

// ================= kernel 2: 96 -> 12 channel mix =================
__global__ __launch_bounds__(256, 8) void conv_reduce_kernel(
    const bf16_t* __restrict__ hsw,  // (96, N, 64)
    const float* __restrict__ cwg,   // (12, 96)
    const float* __restrict__ cbg,   // (12)
    float* __restrict__ outg)        // (12, N, 64)
{
    int flat = blockIdx.x * 256 + threadIdx.x;   // N*32 threads
    int n  = flat >> 5;
    int h2 = (flat & 31) * 2;
    float a0[T_LEN], a1[T_LEN];
    #pragma unroll
    for (int o = 0; o < T_LEN; ++o) { float b = cbg[o]; a0[o] = b; a1[o] = b; }
    const bf16_t* src = hsw + (size_t)n * HD + h2;
    #pragma unroll 8
    for (int c = 0; c < NHEADS * T_LEN; ++c) {
        bf16x2 hv = *(const bf16x2*)(src + (size_t)c * NNODES * HD);
        float h0 = (float)hv[0], h1 = (float)hv[1];
        #pragma unroll
        for (int o = 0; o < T_LEN; ++o) {
            float cv = cwg[o * (NHEADS * T_LEN) + c];
            a0[o] += cv * h0;
            a1[o] += cv * h1;
        }
    }
    #pragma unroll
    for (int o = 0; o < T_LEN; ++o) {
        f32x2 v = {a0[o], a1[o]};
        *(f32x2*)(outg + ((size_t)o * NNODES + n) * HD + h2) = v;
    }
}

// ============ fallback: R2's proven monolithic kernel (fp32 I/O) ============
struct SmemT {
    __align__(16) bf16_t xT[T_LEN][MT][LDSP];
    __align__(16) bf16_t hA[2][2][MT][LDSP];
    __align__(16) float  cwf[T_LEN][NHEADS * T_LEN];
    __align__(16) float  cbf[T_LEN];
};

__global__ __launch_bounds__(256) void lstm_mono_kernel(
    const float* __restrict__ xg, const float* __restrict__ Wih,
    const float* __restrict__ Whh, const float* __restrict__ bih,
    const float* __restrict__ bhh, const float* __restrict__ h0g,
    const float* __restrict__ c0g, const float* __restrict__ cwg,
    const float* __restrict__ cbg, float* __restrict__ outg)
{
    __shared__ SmemT s;
    const int tid  = threadIdx.x;
    const int w    = tid >> 6;
    const int lane = tid & 63;
    const int quad = lane >> 4;
    const int col  = lane & 15;
    const int nb   = blockIdx.x * MT;

    #pragma unroll
    for (int it = 0; it < 6; ++it) {
        int ci   = it * 256 + tid;
        int e    = ci * 8;
        int t    = e >> 10;
        int node = (e >> 6) & (MT - 1);
        int f    = e & (HD - 1);
        *(bf16x8*)&s.xT[t][node][f] =
            load8f(xg + ((size_t)t * NNODES + nb + node) * HD + f);
    }
    for (int i = tid; i < T_LEN * NHEADS * T_LEN; i += 256)
        s.cwf[i / 96][i % 96] = cwg[i];
    if (tid < T_LEN) s.cbf[tid] = cbg[tid];

    float conv_acc[T_LEN][4];
    #pragma unroll
    for (int o = 0; o < T_LEN; ++o)
        #pragma unroll
        for (int r = 0; r < 4; ++r) conv_acc[o][r] = 0.0f;

    #pragma unroll 1
    for (int a = 0; a < NHEADS; ++a) {
        bf16x8 wih[2][4][2], whh[2][4][2];
        #pragma unroll
        for (int l = 0; l < 2; ++l)
            #pragma unroll
            for (int ni = 0; ni < 4; ++ni)
                #pragma unroll
                for (int kf = 0; kf < 2; ++kf) {
                    size_t off = (((size_t)l * NHEADS + a) * 256 + (4 * ni + w) * 16 + col) * HD
                               + kf * 32 + quad * 8;
                    wih[l][ni][kf] = load8f(Wih + off);
                    whh[l][ni][kf] = load8f(Whh + off);
                }
        float bias[2][4];
        #pragma unroll
        for (int l = 0; l < 2; ++l)
            #pragma unroll
            for (int ni = 0; ni < 4; ++ni) {
                int off = (l * NHEADS + a) * 256 + ni * 64 + w * 16 + col;
                bias[l][ni] = bih[off] + bhh[off];
            }
        float creg[2][4];
        #pragma unroll
        for (int l = 0; l < 2; ++l)
            #pragma unroll
            for (int r = 0; r < 4; ++r)
                creg[l][r] = c0g[(((size_t)a * 2 + l) * NNODES + nb + quad * 4 + r) * HD
                                 + w * 16 + col];
        {
            int e    = tid * 8;
            int l    = e >> 10;
            int node = (e >> 6) & (MT - 1);
            int hh   = e & (HD - 1);
            *(bf16x8*)&s.hA[l][0][node][hh] =
                load8f(h0g + (((size_t)a * 2 + l) * NNODES + nb + node) * HD + hh);
        }
        __syncthreads();

        int cur = 0;
        #pragma unroll 1
        for (int t = 0; t < T_LEN; ++t) {
            bf16x8 xa0 = *(const bf16x8*)&s.xT[t][col][quad * 8];
            bf16x8 xa1 = *(const bf16x8*)&s.xT[t][col][32 + quad * 8];
            bf16x8 ha0 = *(const bf16x8*)&s.hA[0][cur][col][quad * 8];
            bf16x8 ha1 = *(const bf16x8*)&s.hA[0][cur][col][32 + quad * 8];
            f32x4 acc[4];
            #pragma unroll
            for (int ni = 0; ni < 4; ++ni) {
                f32x4 z = {0.f, 0.f, 0.f, 0.f};
                z = MFMA16(xa0, wih[0][ni][0], z);
                z = MFMA16(xa1, wih[0][ni][1], z);
                z = MFMA16(ha0, whh[0][ni][0], z);
                z = MFMA16(ha1, whh[0][ni][1], z);
                acc[ni] = z;
            }
            #pragma unroll
            for (int r = 0; r < 4; ++r) {
                float ig = fast_sigmoid(acc[0][r] + bias[0][0]);
                float fg = fast_sigmoid(acc[1][r] + bias[0][1]);
                float gg = fast_tanh   (acc[2][r] + bias[0][2]);
                float og = fast_sigmoid(acc[3][r] + bias[0][3]);
                float cn = fg * creg[0][r] + ig * gg;
                creg[0][r] = cn;
                s.hA[0][cur ^ 1][quad * 4 + r][w * 16 + col] = (bf16_t)(og * fast_tanh(cn));
            }
            __syncthreads();
            bf16x8 pa0 = *(const bf16x8*)&s.hA[0][cur ^ 1][col][quad * 8];
            bf16x8 pa1 = *(const bf16x8*)&s.hA[0][cur ^ 1][col][32 + quad * 8];
            bf16x8 qa0 = *(const bf16x8*)&s.hA[1][cur][col][quad * 8];
            bf16x8 qa1 = *(const bf16x8*)&s.hA[1][cur][col][32 + quad * 8];
            #pragma unroll
            for (int ni = 0; ni < 4; ++ni) {
                f32x4 z = {0.f, 0.f, 0.f, 0.f};
                z = MFMA16(pa0, wih[1][ni][0], z);
                z = MFMA16(pa1, wih[1][ni][1], z);
                z = MFMA16(qa0, whh[1][ni][0], z);
                z = MFMA16(qa1, whh[1][ni][1], z);
                acc[ni] = z;
            }
            float hn[4];
            #pragma unroll
            for (int r = 0; r < 4; ++r) {
                float ig = fast_sigmoid(acc[0][r] + bias[1][0]);
                float fg = fast_sigmoid(acc[1][r] + bias[1][1]);
                float gg = fast_tanh   (acc[2][r] + bias[1][2]);
                float og = fast_sigmoid(acc[3][r] + bias[1][3]);
                float cn = fg * creg[1][r] + ig * gg;
                creg[1][r] = cn;
                hn[r] = og * fast_tanh(cn);
                s.hA[1][cur ^ 1][quad * 4 + r][w * 16 + col] = (bf16_t)hn[r];
            }
            #pragma unroll
            for (int o = 0; o < T_LEN; ++o) {
                float cv = s.cwf[o][a * T_LEN + t];
                #pragma unroll
                for (int r = 0; r < 4; ++r) conv_acc[o][r] += cv * hn[r];
            }
            __syncthreads();
            cur ^= 1;
        }
    }
    #pragma unroll
    for (int o = 0; o < T_LEN; ++o)
        #pragma unroll
        for (int r = 0; r < 4; ++r)
            outg[((size_t)o * NNODES + nb + quad * 4 + r) * HD + w * 16 + col] =
                conv_acc[o][r] + s.cbf[o];
}

extern "C" void kernel_launch(void* const* d_in, const int* in_sizes, int n_in,
                              void* d_out, int out_size, void* d_ws, size_t ws_size,
                              hipStream_t stream) {
    (void)in_sizes; (void)n_in; (void)out_size;
    const float* x   = (const float*)d_in[0];
    const float* Wih = (const float*)d_in[1];
    const float* Whh = (const float*)d_in[2];
    const float* bih = (const float*)d_in[3];
    const float* bhh = (const float*)d_in[4];
    const float* h0  = (const float*)d_in[5];
    const float* c0  = (const float*)d_in[6];
    const float* cw  = (const float*)d_in[7];
    const float* cb  = (const float*)d_in[8];
    const size_t hs_bytes = (size_t)NHEADS * T_LEN * NNODES * HD * sizeof(bf16_t);
    const size_t x_bytes  = (size_t)T_LEN * NNODES * HD * sizeof(bf16_t);
    const size_t w_bytes  = (size_t)2 * WIH_ELEMS * sizeof(bf16_t);
    if (ws_size >= hs_bytes + x_bytes + w_bytes) {
        bf16_t* hs  = (bf16_t*)d_ws;
        bf16_t* xbf = (bf16_t*)((char*)d_ws + hs_bytes);
        bf16_t* wbf = (bf16_t*)((char*)d_ws + hs_bytes + x_bytes);
        const int n8x = T_LEN * NNODES * HD / 8;
        const int n8w = WIH_ELEMS / 8;
        cvt_bf16_kernel<<<dim3(n8x / 256), dim3(256), 0, stream>>>(x, xbf, n8x);
        cvt_bf16_kernel<<<dim3((n8w + 255) / 256), dim3(256), 0, stream>>>(Wih, wbf, n8w);
        cvt_bf16_kernel<<<dim3((n8w + 255) / 256), dim3(256), 0, stream>>>(Whh, wbf + WIH_ELEMS, n8w);
        lstm_pipe_kernel<true><<<dim3((NNODES / MT) * NHEADS), dim3(512), 0, stream>>>(
            x, xbf, Wih, Whh, wbf, bih, bhh, h0, c0, hs);
        conv_reduce_kernel<<<dim3(NNODES * 32 / 256), dim3(256), 0, stream>>>(
            hs, cw, cb, (float*)d_out);
    } else if (ws_size >= hs_bytes) {
        bf16_t* hs = (bf16_t*)d_ws;
        lstm_pipe_kernel<false><<<dim3((NNODES / MT) * NHEADS), dim3(512), 0, stream>>>(
            x, nullptr, Wih, Whh, nullptr, bih, bhh, h0, c0, hs);
        conv_reduce_kernel<<<dim3(NNODES * 32 / 256), dim3(256), 0, stream>>>(
            hs, cw, cb, (float*)d_out);
    } else {
        lstm_mono_kernel<<<dim3(NNODES / MT), dim3(256), 0, stream>>>(
            x, Wih, Whh, bih, bhh, h0, c0, cw, cb, (float*)d_out);
    }
}

// Round 2
// 533.686 us; speedup vs baseline: 1.3721x; 1.0270x over previous
//
#include <hip/hip_runtime.h>
#include <hip/hip_bf16.h>

// LSTMblock: 2-layer, 8-head LSTM (H=F=64, T=12) over N=16384 nodes, then
// 1x1 conv mixing (head,t) channels (96 -> 12). fp32 I/O, bf16 MFMA, fp32 cell.
//
// R6: R5 counters: VALUBusy 71.6% (top pipe), MfmaUtil 24%, HBM 12%, VGPR=64
// arch (+~64 AGPR for weight frags -> 128/wave -> 4 waves/SIMD, matches 45%
// occupancy). VALU bill: 16 scalar ds_write_b16 h-writes + 4 cvts (D-rows
// non-contiguous), 8 __expf pre-muls, hs LDS-read+store path.
// Changes: (1) MFMA operand swap D = W*h^T -- load layouts are bit-identical
// (W B-frag == W A-frag, h A-frag == h^T B-frag), but each lane's D holds 4
// CONSECUTIVE h-cols of one node -> h-write is one ds_write_b64, and l1 waves
// store hs direct-from-register to global (no LDS round trip, no epilogue).
// (2) log2e folded into weights/bias at prep (g-gate rows x 2log2e): gate
// exp = raw v_exp with neg modifier, no pre-mul. (3) bias (now per-row f32x4)
// lives in LDS, read as broadcast C-init -- keeps total regs <= 128/wave.
// (4) conv: 4 h/thread (8B loads) + unroll 6.
//
// MFMA v_mfma_f32_16x16x32_bf16 lane mapping (m89/m120-verified):
//   A[m][k]: lane(quad,col) reg j holds A[m=col][k=quad*8+j]
//   B[k][n]: lane reg j holds B[k=quad*8+j][n=col]
//   D[m][n]: lane reg r holds D[m=quad*4+r][n=col]

#define T_LEN 12
#define NHEADS 8
#define HD 64
#define NNODES 16384
#define MT 16
#define LDSP 72
#define WIH_ELEMS (2 * NHEADS * 4 * HD * HD)   // 262144 elems per weight tensor

typedef __bf16 bf16_t;
typedef __attribute__((ext_vector_type(2))) __bf16 bf16x2;
typedef __attribute__((ext_vector_type(4))) __bf16 bf16x4;
typedef __attribute__((ext_vector_type(8))) __bf16 bf16x8;
typedef __attribute__((ext_vector_type(4))) float f32x4;

#define MFMA16(a, b, c) __builtin_amdgcn_mfma_f32_16x16x32_bf16((a), (b), (c), 0, 0, 0)

#if __has_builtin(__builtin_amdgcn_exp2f)
#define EXP2(x) __builtin_amdgcn_exp2f(x)
#else
#define EXP2(x) exp2f(x)
#endif

__device__ __forceinline__ float fast_sigmoid(float v) {
    return __builtin_amdgcn_rcpf(1.0f + __expf(-v));
}
__device__ __forceinline__ float fast_tanh(float v) {
    return 2.0f * __builtin_amdgcn_rcpf(1.0f + __expf(-2.0f * v)) - 1.0f;
}

__device__ __forceinline__ bf16x8 load8f(const float* p) {
    f32x4 a = *(const f32x4*)p;
    f32x4 b = *(const f32x4*)(p + 4);
    bf16x8 r;
    r[0] = (bf16_t)a[0]; r[1] = (bf16_t)a[1]; r[2] = (bf16_t)a[2]; r[3] = (bf16_t)a[3];
    r[4] = (bf16_t)b[0]; r[5] = (bf16_t)b[1]; r[6] = (bf16_t)b[2]; r[7] = (bf16_t)b[3];
    return r;
}
__device__ __forceinline__ bf16x4 load4f(const float* p) {
    f32x4 a = *(const f32x4*)p;
    bf16x4 r;
    r[0] = (bf16_t)a[0]; r[1] = (bf16_t)a[1]; r[2] = (bf16_t)a[2]; r[3] = (bf16_t)a[3];
    return r;
}

// Gate pointwise for 4 rows (one lane: node=col, hcols wq*16+quad*4 .. +3).
// SC=true: gate pre-acts arrive PRE-SCALED by log2e (2*log2e for g) -> raw
// exp2 with free neg modifier. One rcp per gate_eval, one per tanh4.
template<bool SC>
__device__ __forceinline__ bf16x4 lstm_pointwise_sw(const f32x4* acc, float* creg) {
    float cn[4], so[4], tc[4];
    #pragma unroll
    for (int r = 0; r < 4; ++r) {
        float ei, ef, eg, eo;
        if (SC) {
            ei = EXP2(-acc[0][r]); ef = EXP2(-acc[1][r]);
            eg = EXP2(-acc[2][r]); eo = EXP2(-acc[3][r]);
        } else {
            ei = __expf(-acc[0][r]); ef = __expf(-acc[1][r]);
            eg = __expf(-2.0f * acc[2][r]); eo = __expf(-acc[3][r]);
        }
        float di = 1.0f + ei, df = 1.0f + ef, dg = 1.0f + eg, do_ = 1.0f + eo;
        float pif = di * df, pgo = dg * do_;
        float rr  = __builtin_amdgcn_rcpf(pif * pgo);
        float rif = rr * pgo, rgo = rr * pif;
        float sig_i  = rif * df;
        float sig_f  = rif * di;
        float tanh_g = 2.0f * (rgo * do_) - 1.0f;
        so[r] = rgo * dg;                      // sig_o
        float cnr = sig_f * creg[r] + sig_i * tanh_g;
        cn[r] = cnr;
        creg[r] = cnr;
    }
    // batched tanh(cn): one shared rcp
    float d0 = 1.0f + EXP2(cn[0] * -2.885390082f);
    float d1 = 1.0f + EXP2(cn[1] * -2.885390082f);
    float d2 = 1.0f + EXP2(cn[2] * -2.885390082f);
    float d3 = 1.0f + EXP2(cn[3] * -2.885390082f);
    float p01 = d0 * d1, p23 = d2 * d3;
    float rr  = __builtin_amdgcn_rcpf(p01 * p23);
    float r01 = rr * p23, r23 = rr * p01;
    tc[0] = 2.0f * (r01 * d1) - 1.0f;
    tc[1] = 2.0f * (r01 * d0) - 1.0f;
    tc[2] = 2.0f * (r23 * d3) - 1.0f;
    tc[3] = 2.0f * (r23 * d2) - 1.0f;
    bf16x4 hv;
    hv[0] = (bf16_t)(so[0] * tc[0]);
    hv[1] = (bf16_t)(so[1] * tc[1]);
    hv[2] = (bf16_t)(so[2] * tc[2]);
    hv[3] = (bf16_t)(so[3] * tc[3]);
    return hv;
}

// ============== prep: fp32 -> bf16 bulk convert ==============
__global__ __launch_bounds__(256) void cvt_bf16_kernel(
    const float* __restrict__ src, bf16_t* __restrict__ dst, int n8)
{
    int i = blockIdx.x * 256 + threadIdx.x;
    if (i < n8) *(bf16x8*)(dst + (size_t)i * 8) = load8f(src + (size_t)i * 8);
}

// weights: scale by log2e (2*log2e for g-gate rows) BEFORE the single bf16
// rounding -> same rounding-error magnitude as unscaled conversion.
__global__ __launch_bounds__(256) void cvt_w_kernel(
    const float* __restrict__ src, bf16_t* __restrict__ dst, int n8)
{
    int i = blockIdx.x * 256 + threadIdx.x;
    if (i >= n8) return;
    int row  = (i >> 3) & 255;           // 8 elems never cross a row (64 % 8 == 0)
    int gate = row >> 6;
    float sc = (gate == 2) ? 2.885390082f : 1.442695041f;
    const float* p = src + (size_t)i * 8;
    f32x4 a = *(const f32x4*)p;
    f32x4 b = *(const f32x4*)(p + 4);
    bf16x8 r;
    r[0] = (bf16_t)(a[0]*sc); r[1] = (bf16_t)(a[1]*sc);
    r[2] = (bf16_t)(a[2]*sc); r[3] = (bf16_t)(a[3]*sc);
    r[4] = (bf16_t)(b[0]*sc); r[5] = (bf16_t)(b[1]*sc);
    r[6] = (bf16_t)(b[2]*sc); r[7] = (bf16_t)(b[3]*sc);
    *(bf16x8*)(dst + (size_t)i * 8) = r;
}

// ====== kernel 1: per-(tile,head) 2-layer LSTM, layer-split waves ======
// 512 threads: waves 0-3 layer0, waves 4-7 layer1, pipelined l0[t] || l1[t-1].
// MFMA computes D = W * h^T: lane holds gates for node=col at 4 consecutive
// gate-cols (wq*16 + quad*4 + r). h-write = 1 ds_write_b64; l1 stores hs
// straight from registers to global.
template<bool PREP>
__global__ __launch_bounds__(512, 4) void lstm_pipe_kernel(
    const float* __restrict__ xg,   // (T, N, 64) fp32
    const bf16_t* __restrict__ xbf, // (T, N, 64) bf16 (PREP)
    const float* __restrict__ Wih,  // (2, 8, 256, 64)
    const float* __restrict__ Whh,  // (2, 8, 256, 64)
    const bf16_t* __restrict__ wbf, // [Wih | Whh] bf16, pre-scaled (PREP)
    const float* __restrict__ bih,  // (2, 8, 256)
    const float* __restrict__ bhh,  // (2, 8, 256)
    const float* __restrict__ h0g,  // (8, 2, N, 64)
    const float* __restrict__ c0g,  // (8, 2, N, 64)
    bf16_t* __restrict__ hsw)       // (96, N, 64) channel-major hs
{
    __shared__ __align__(16) bf16_t xT[T_LEN][MT][LDSP];   // x tile
    __shared__ __align__(16) bf16_t h0A[2][MT][LDSP];      // layer0 h, dbuf
    __shared__ __align__(16) bf16_t h1A[2][MT][LDSP];      // layer1 h, dbuf
    __shared__ __align__(16) float  biasLds[2][4][4][16];  // [layer][wq][gate][gc]

    const int tid  = threadIdx.x;
    const int w    = tid >> 6;
    const int lane = tid & 63;
    const int quad = lane >> 4;
    const int col  = lane & 15;
    const int lw   = w >> 2;        // layer this wave serves
    const int wq   = w & 3;         // gate n-tile group within the layer
    const int a    = blockIdx.x & (NHEADS - 1);
    const int nb   = (blockIdx.x >> 3) * MT;

    // ---- x tile -> LDS ----
    #pragma unroll
    for (int it = 0; it < 3; ++it) {
        int e    = (it * 512 + tid) * 8;
        int t    = e >> 10;
        int node = (e >> 6) & (MT - 1);
        int f    = e & (HD - 1);
        bf16x8 v;
        if (PREP) v = *(const bf16x8*)(xbf + ((size_t)t * NNODES + nb + node) * HD + f);
        else      v = load8f(xg + ((size_t)t * NNODES + nb + node) * HD + f);
        *(bf16x8*)&xT[t][node][f] = v;
    }
    // ---- h0 init: layer0 -> h0A[0], layer1 -> h1A[1] ----
    {
        int e    = tid * 4;
        int l    = e >> 10;
        int node = (e >> 6) & (MT - 1);
        int hh   = e & (HD - 1);
        bf16x4 v = load4f(h0g + (((size_t)a * 2 + l) * NNODES + nb + node) * HD + hh);
        if (l == 0) *(bf16x4*)&h0A[0][node][hh] = v;
        else        *(bf16x4*)&h1A[1][node][hh] = v;
    }
    // ---- bias -> LDS (scaled to exp2 domain for PREP) ----
    {
        int l   = tid >> 8;
        int r   = tid & 255;
        int wqi = r >> 6;
        int nii = (r >> 4) & 3;
        int gc  = r & 15;
        int off = (l * NHEADS + a) * 256 + nii * 64 + wqi * 16 + gc;
        float sc = PREP ? (nii == 2 ? 2.885390082f : 1.442695041f) : 1.0f;
        biasLds[l][wqi][nii][gc] = (bih[off] + bhh[off]) * sc;
    }

    // ---- this wave's layer weights as A-frags (same bits as old B-frags) ----
    bf16x8 wA[4][2], wB[4][2];      // [gate i/f/g/o][kfrag]; A=W_ih, B=W_hh
    #pragma unroll
    for (int ni = 0; ni < 4; ++ni)
        #pragma unroll
        for (int kf = 0; kf < 2; ++kf) {
            size_t off = (((size_t)lw * NHEADS + a) * 256 + (4 * ni + wq) * 16 + col) * HD
                       + kf * 32 + quad * 8;
            if (PREP) {
                wA[ni][kf] = *(const bf16x8*)(wbf + off);
                wB[ni][kf] = *(const bf16x8*)(wbf + WIH_ELEMS + off);
            } else {
                wA[ni][kf] = load8f(Wih + off);
                wB[ni][kf] = load8f(Whh + off);
            }
        }
    // cell state for (node=col, hcol = wq*16 + quad*4 + r)
    float creg[4];
    {
        f32x4 cv = *(const f32x4*)(c0g + (((size_t)a * 2 + lw) * NNODES + nb + col) * HD
                                   + wq * 16 + quad * 4);
        creg[0] = cv[0]; creg[1] = cv[1]; creg[2] = cv[2]; creg[3] = cv[3];
    }
    __syncthreads();

    int cur = 0;
    #pragma unroll 1
    for (int p = 0; p <= T_LEN; ++p) {
        const bool active = lw ? (p >= 1) : (p < T_LEN);
        if (active) {
            // l0: gates = Wih0*x[p]^T   + Whh0*h_l0[p-1]^T
            // l1: gates = Wih1*h_l0[p-1]^T + Whh1*h_l1[p-2]^T
            const bf16_t* P = lw ? &h0A[cur][0][0] : &xT[p][0][0];
            const bf16_t* Q = lw ? &h1A[cur][0][0] : &h0A[cur][0][0];
            bf16_t*       D = lw ? &h1A[cur ^ 1][0][0] : &h0A[cur ^ 1][0][0];
            const int ro = col * LDSP + quad * 8;
            bf16x8 a0 = *(const bf16x8*)(P + ro);
            bf16x8 b0 = *(const bf16x8*)(Q + ro);
            f32x4 acc[4];
            #pragma unroll
            for (int ni = 0; ni < 4; ++ni) {
                f32x4 z = *(const f32x4*)&biasLds[lw][wq][ni][quad * 4];  // broadcast
                z = MFMA16(wA[ni][0], a0, z);
                acc[ni] = MFMA16(wB[ni][0], b0, z);
            }
            bf16x8 a1 = *(const bf16x8*)(P + ro + 32);
            bf16x8 b1 = *(const bf16x8*)(Q + ro + 32);
            #pragma unroll
            for (int ni = 0; ni < 4; ++ni) {
                f32x4 z = MFMA16(wA[ni][1], a1, acc[ni]);
                acc[ni] = MFMA16(wB[ni][1], b1, z);
            }
            bf16x4 hv = lstm_pointwise_sw<PREP>(acc, creg);
            *(bf16x4*)(D + col * LDSP + wq * 16 + quad * 4) = hv;   // one b64 write
            if (lw)   // hs store direct from registers (t = p-1)
                *(bf16x4*)(hsw + ((size_t)(a * T_LEN + (p - 1)) * NNODES + nb + col) * HD
                           + wq * 16 + quad * 4) = hv;
        }
        __syncthreads();
        cur ^= 1;
    }
}

// ================= kernel 2: 96 -> 12 channel mix =================
__global__ __launch_bounds__(256) void conv_reduce_kernel(
    const bf16_t* __restrict__ hsw,  // (96, N, 64)
    const float* __restrict__ cwg,   // (12, 96)
    const float* __restrict__ cbg,   // (12)
    float* __restrict__ outg)        // (12, N, 64)
{
    int flat = blockIdx.x * 256 + threadIdx.x;   // N*16 threads
    int n  = flat >> 4;
    int h4 = (flat & 15) * 4;
    f32x4 acc[T_LEN];
    #pragma unroll
    for (int o = 0; o < T_LEN; ++o) {
        float b = cbg[o];
        acc[o][0] = b; acc[o][1] = b; acc[o][2] = b; acc[o][3] = b;
    }
    const bf16_t* src = hsw + (size_t)n * HD + h4;
    #pragma unroll 6
    for (int c = 0; c < NHEADS * T_LEN; ++c) {
        bf16x4 hv = *(const bf16x4*)(src + (size_t)c * NNODES * HD);
        float h0 = (float)hv[0], h1 = (float)hv[1], h2 = (float)hv[2], h3 = (float)hv[3];
        #pragma unroll
        for (int o = 0; o < T_LEN; ++o) {
            float cv = cwg[o * (NHEADS * T_LEN) + c];
            acc[o][0] += cv * h0; acc[o][1] += cv * h1;
            acc[o][2] += cv * h2; acc[o][3] += cv * h3;
        }
    }
    #pragma unroll
    for (int o = 0; o < T_LEN; ++o)
        *(f32x4*)(outg + ((size_t)o * NNODES + n) * HD + h4) = acc[o];
}

// ============ fallback: R2's proven monolithic kernel (fp32 I/O) ============
struct SmemT {
    __align__(16) bf16_t xT[T_LEN][MT][LDSP];
    __align__(16) bf16_t hA[2][2][MT][LDSP];
    __align__(16) float  cwf[T_LEN][NHEADS * T_LEN];
    __align__(16) float  cbf[T_LEN];
};

__global__ __launch_bounds__(256) void lstm_mono_kernel(
    const float* __restrict__ xg, const float* __restrict__ Wih,
    const float* __restrict__ Whh, const float* __restrict__ bih,
    const float* __restrict__ bhh, const float* __restrict__ h0g,
    const float* __restrict__ c0g, const float* __restrict__ cwg,
    const float* __restrict__ cbg, float* __restrict__ outg)
{
    __shared__ SmemT s;
    const int tid  = threadIdx.x;
    const int w    = tid >> 6;
    const int lane = tid & 63;
    const int quad = lane >> 4;
    const int col  = lane & 15;
    const int nb   = blockIdx.x * MT;

    #pragma unroll
    for (int it = 0; it < 6; ++it) {
        int ci   = it * 256 + tid;
        int e    = ci * 8;
        int t    = e >> 10;
        int node = (e >> 6) & (MT - 1);
        int f    = e & (HD - 1);
        *(bf16x8*)&s.xT[t][node][f] =
            load8f(xg + ((size_t)t * NNODES + nb + node) * HD + f);
    }
    for (int i = tid; i < T_LEN * NHEADS * T_LEN; i += 256)
        s.cwf[i / 96][i % 96] = cwg[i];
    if (tid < T_LEN) s.cbf[tid] = cbg[tid];

    float conv_acc[T_LEN][4];
    #pragma unroll
    for (int o = 0; o < T_LEN; ++o)
        #pragma unroll
        for (int r = 0; r < 4; ++r) conv_acc[o][r] = 0.0f;

    #pragma unroll 1
    for (int a = 0; a < NHEADS; ++a) {
        bf16x8 wih[2][4][2], whh[2][4][2];
        #pragma unroll
        for (int l = 0; l < 2; ++l)
            #pragma unroll
            for (int ni = 0; ni < 4; ++ni)
                #pragma unroll
                for (int kf = 0; kf < 2; ++kf) {
                    size_t off = (((size_t)l * NHEADS + a) * 256 + (4 * ni + w) * 16 + col) * HD
                               + kf * 32 + quad * 8;
                    wih[l][ni][kf] = load8f(Wih + off);
                    whh[l][ni][kf] = load8f(Whh + off);
                }
        float bias[2][4];
        #pragma unroll
        for (int l = 0; l < 2; ++l)
            #pragma unroll
            for (int ni = 0; ni < 4; ++ni) {
                int off = (l * NHEADS + a) * 256 + ni * 64 + w * 16 + col;
                bias[l][ni] = bih[off] + bhh[off];
            }
        float creg[2][4];
        #pragma unroll
        for (int l = 0; l < 2; ++l)
            #pragma unroll
            for (int r = 0; r < 4; ++r)
                creg[l][r] = c0g[(((size_t)a * 2 + l) * NNODES + nb + quad * 4 + r) * HD
                                 + w * 16 + col];
        {
            int e    = tid * 8;
            int l    = e >> 10;
            int node = (e >> 6) & (MT - 1);
            int hh   = e & (HD - 1);
            *(bf16x8*)&s.hA[l][0][node][hh] =
                load8f(h0g + (((size_t)a * 2 + l) * NNODES + nb + node) * HD + hh);
        }
        __syncthreads();

        int cur = 0;
        #pragma unroll 1
        for (int t = 0; t < T_LEN; ++t) {
            bf16x8 xa0 = *(const bf16x8*)&s.xT[t][col][quad * 8];
            bf16x8 xa1 = *(const bf16x8*)&s.xT[t][col][32 + quad * 8];
            bf16x8 ha0 = *(const bf16x8*)&s.hA[0][cur][col][quad * 8];
            bf16x8 ha1 = *(const bf16x8*)&s.hA[0][cur][col][32 + quad * 8];
            f32x4 acc[4];
            #pragma unroll
            for (int ni = 0; ni < 4; ++ni) {
                f32x4 z = {0.f, 0.f, 0.f, 0.f};
                z = MFMA16(xa0, wih[0][ni][0], z);
                z = MFMA16(xa1, wih[0][ni][1], z);
                z = MFMA16(ha0, whh[0][ni][0], z);
                z = MFMA16(ha1, whh[0][ni][1], z);
                acc[ni] = z;
            }
            #pragma unroll
            for (int r = 0; r < 4; ++r) {
                float ig = fast_sigmoid(acc[0][r] + bias[0][0]);
                float fg = fast_sigmoid(acc[1][r] + bias[0][1]);
                float gg = fast_tanh   (acc[2][r] + bias[0][2]);
                float og = fast_sigmoid(acc[3][r] + bias[0][3]);
                float cn = fg * creg[0][r] + ig * gg;
                creg[0][r] = cn;
                s.hA[0][cur ^ 1][quad * 4 + r][w * 16 + col] = (bf16_t)(og * fast_tanh(cn));
            }
            __syncthreads();
            bf16x8 pa0 = *(const bf16x8*)&s.hA[0][cur ^ 1][col][quad * 8];
            bf16x8 pa1 = *(const bf16x8*)&s.hA[0][cur ^ 1][col][32 + quad * 8];
            bf16x8 qa0 = *(const bf16x8*)&s.hA[1][cur][col][quad * 8];
            bf16x8 qa1 = *(const bf16x8*)&s.hA[1][cur][col][32 + quad * 8];
            #pragma unroll
            for (int ni = 0; ni < 4; ++ni) {
                f32x4 z = {0.f, 0.f, 0.f, 0.f};
                z = MFMA16(pa0, wih[1][ni][0], z);
                z = MFMA16(pa1, wih[1][ni][1], z);
                z = MFMA16(qa0, whh[1][ni][0], z);
                z = MFMA16(qa1, whh[1][ni][1], z);
                acc[ni] = z;
            }
            float hn[4];
            #pragma unroll
            for (int r = 0; r < 4; ++r) {
                float ig = fast_sigmoid(acc[0][r] + bias[1][0]);
                float fg = fast_sigmoid(acc[1][r] + bias[1][1]);
                float gg = fast_tanh   (acc[2][r] + bias[1][2]);
                float og = fast_sigmoid(acc[3][r] + bias[1][3]);
                float cn = fg * creg[1][r] + ig * gg;
                creg[1][r] = cn;
                hn[r] = og * fast_tanh(cn);
                s.hA[1][cur ^ 1][quad * 4 + r][w * 16 + col] = (bf16_t)hn[r];
            }
            #pragma unroll
            for (int o = 0; o < T_LEN; ++o) {
                float cv = s.cwf[o][a * T_LEN + t];
                #pragma unroll
                for (int r = 0; r < 4; ++r) conv_acc[o][r] += cv * hn[r];
            }
            __syncthreads();
            cur ^= 1;
        }
    }
    #pragma unroll
    for (int o = 0; o < T_LEN; ++o)
        #pragma unroll
        for (int r = 0; r < 4; ++r)
            outg[((size_t)o * NNODES + nb + quad * 4 + r) * HD + w * 16 + col] =
                conv_acc[o][r] + s.cbf[o];
}

extern "C" void kernel_launch(void* const* d_in, const int* in_sizes, int n_in,
                              void* d_out, int out_size, void* d_ws, size_t ws_size,
                              hipStream_t stream) {
    (void)in_sizes; (void)n_in; (void)out_size;
    const float* x   = (const float*)d_in[0];
    const float* Wih = (const float*)d_in[1];
    const float* Whh = (const float*)d_in[2];
    const float* bih = (const float*)d_in[3];
    const float* bhh = (const float*)d_in[4];
    const float* h0  = (const float*)d_in[5];
    const float* c0  = (const float*)d_in[6];
    const float* cw  = (const float*)d_in[7];
    const float* cb  = (const float*)d_in[8];
    const size_t hs_bytes = (size_t)NHEADS * T_LEN * NNODES * HD * sizeof(bf16_t);
    const size_t x_bytes  = (size_t)T_LEN * NNODES * HD * sizeof(bf16_t);
    const size_t w_bytes  = (size_t)2 * WIH_ELEMS * sizeof(bf16_t);
    if (ws_size >= hs_bytes + x_bytes + w_bytes) {
        bf16_t* hs  = (bf16_t*)d_ws;
        bf16_t* xbf = (bf16_t*)((char*)d_ws + hs_bytes);
        bf16_t* wbf = (bf16_t*)((char*)d_ws + hs_bytes + x_bytes);
        const int n8x = T_LEN * NNODES * HD / 8;
        const int n8w = WIH_ELEMS / 8;
        cvt_bf16_kernel<<<dim3(n8x / 256), dim3(256), 0, stream>>>(x, xbf, n8x);
        cvt_w_kernel<<<dim3((n8w + 255) / 256), dim3(256), 0, stream>>>(Wih, wbf, n8w);
        cvt_w_kernel<<<dim3((n8w + 255) / 256), dim3(256), 0, stream>>>(Whh, wbf + WIH_ELEMS, n8w);
        lstm_pipe_kernel<true><<<dim3((NNODES / MT) * NHEADS), dim3(512), 0, stream>>>(
            x, xbf, Wih, Whh, wbf, bih, bhh, h0, c0, hs);
        conv_reduce_kernel<<<dim3(NNODES * 16 / 256), dim3(256), 0, stream>>>(
            hs, cw, cb, (float*)d_out);
    } else if (ws_size >= hs_bytes) {
        bf16_t* hs = (bf16_t*)d_ws;
        lstm_pipe_kernel<false><<<dim3((NNODES / MT) * NHEADS), dim3(512), 0, stream>>>(
            x, nullptr, Wih, Whh, nullptr, bih, bhh, h0, c0, hs);
        conv_reduce_kernel<<<dim3(NNODES * 16 / 256), dim3(256), 0, stream>>>(
            hs, cw, cb, (float*)d_out);
    } else {
        lstm_mono_kernel<<<dim3(NNODES / MT), dim3(256), 0, stream>>>(
            x, Wih, Whh, bih, bhh, h0, c0, cw, cb, (float*)d_out);
    }
}

// Round 3
// 514.818 us; speedup vs baseline: 1.4223x; 1.0366x over previous
//
#include <hip/hip_runtime.h>
#include <hip/hip_bf16.h>

// LSTMblock: 2-layer, 8-head LSTM (H=F=64, T=12) over N=16384 nodes, then
// 1x1 conv mixing (head,t) channels (96 -> 12). fp32 I/O, bf16 MFMA, fp32 cell.
//
// R7: R6 showed dur flat (377us) despite -16% VALU -> not VALU-throughput
// bound. Model: 2 blocks/CU resident, ~4.3k cyc/barrier-phase vs ~700 cyc of
// work; the per-phase l1 global hs store forces s_waitcnt vmcnt(0) before
// every s_barrier (store-ack drain ~300-900 cyc, nothing to hide it).
// Change (single variable): NO global ops inside the t-loop. h1 history kept
// in LDS (h1H[13][16][72], replaces h1 dbuf + per-phase store + 64b addr
// math); bulk coalesced hs store after the final barrier (3 bf16x8/thread).
// Pre-barrier waits are now lgkmcnt-only. LDS 62.8KB/block (2 blocks/CU).
//
// MFMA v_mfma_f32_16x16x32_bf16 lane mapping (m89/m120-verified):
//   A[m][k]: lane(quad,col) reg j holds A[m=col][k=quad*8+j]
//   B[k][n]: lane reg j holds B[k=quad*8+j][n=col]
//   D[m][n]: lane reg r holds D[m=quad*4+r][n=col]
// Swapped form D = W*h^T: lane holds gates for node=col at 4 consecutive
// gate-cols (wq*16 + quad*4 + r); h-write is one ds_write_b64.

#define T_LEN 12
#define NHEADS 8
#define HD 64
#define NNODES 16384
#define MT 16
#define LDSP 72
#define WIH_ELEMS (2 * NHEADS * 4 * HD * HD)   // 262144 elems per weight tensor

typedef __bf16 bf16_t;
typedef __attribute__((ext_vector_type(2))) __bf16 bf16x2;
typedef __attribute__((ext_vector_type(4))) __bf16 bf16x4;
typedef __attribute__((ext_vector_type(8))) __bf16 bf16x8;
typedef __attribute__((ext_vector_type(4))) float f32x4;

#define MFMA16(a, b, c) __builtin_amdgcn_mfma_f32_16x16x32_bf16((a), (b), (c), 0, 0, 0)

#if __has_builtin(__builtin_amdgcn_exp2f)
#define EXP2(x) __builtin_amdgcn_exp2f(x)
#else
#define EXP2(x) exp2f(x)
#endif

__device__ __forceinline__ float fast_sigmoid(float v) {
    return __builtin_amdgcn_rcpf(1.0f + __expf(-v));
}
__device__ __forceinline__ float fast_tanh(float v) {
    return 2.0f * __builtin_amdgcn_rcpf(1.0f + __expf(-2.0f * v)) - 1.0f;
}

__device__ __forceinline__ bf16x8 load8f(const float* p) {
    f32x4 a = *(const f32x4*)p;
    f32x4 b = *(const f32x4*)(p + 4);
    bf16x8 r;
    r[0] = (bf16_t)a[0]; r[1] = (bf16_t)a[1]; r[2] = (bf16_t)a[2]; r[3] = (bf16_t)a[3];
    r[4] = (bf16_t)b[0]; r[5] = (bf16_t)b[1]; r[6] = (bf16_t)b[2]; r[7] = (bf16_t)b[3];
    return r;
}
__device__ __forceinline__ bf16x4 load4f(const float* p) {
    f32x4 a = *(const f32x4*)p;
    bf16x4 r;
    r[0] = (bf16_t)a[0]; r[1] = (bf16_t)a[1]; r[2] = (bf16_t)a[2]; r[3] = (bf16_t)a[3];
    return r;
}

// Gate pointwise for 4 rows (one lane: node=col, hcols wq*16+quad*4 .. +3).
// SC=true: gate pre-acts arrive PRE-SCALED by log2e (2*log2e for g) -> raw
// exp2 with free neg modifier. One rcp per row + one shared for tanh4.
template<bool SC>
__device__ __forceinline__ bf16x4 lstm_pointwise_sw(const f32x4* acc, float* creg) {
    float cn[4], so[4], tc[4];
    #pragma unroll
    for (int r = 0; r < 4; ++r) {
        float ei, ef, eg, eo;
        if (SC) {
            ei = EXP2(-acc[0][r]); ef = EXP2(-acc[1][r]);
            eg = EXP2(-acc[2][r]); eo = EXP2(-acc[3][r]);
        } else {
            ei = __expf(-acc[0][r]); ef = __expf(-acc[1][r]);
            eg = __expf(-2.0f * acc[2][r]); eo = __expf(-acc[3][r]);
        }
        float di = 1.0f + ei, df = 1.0f + ef, dg = 1.0f + eg, do_ = 1.0f + eo;
        float pif = di * df, pgo = dg * do_;
        float rr  = __builtin_amdgcn_rcpf(pif * pgo);
        float rif = rr * pgo, rgo = rr * pif;
        float sig_i  = rif * df;
        float sig_f  = rif * di;
        float tanh_g = 2.0f * (rgo * do_) - 1.0f;
        so[r] = rgo * dg;                      // sig_o
        float cnr = sig_f * creg[r] + sig_i * tanh_g;
        cn[r] = cnr;
        creg[r] = cnr;
    }
    // batched tanh(cn): one shared rcp
    float d0 = 1.0f + EXP2(cn[0] * -2.885390082f);
    float d1 = 1.0f + EXP2(cn[1] * -2.885390082f);
    float d2 = 1.0f + EXP2(cn[2] * -2.885390082f);
    float d3 = 1.0f + EXP2(cn[3] * -2.885390082f);
    float p01 = d0 * d1, p23 = d2 * d3;
    float rr  = __builtin_amdgcn_rcpf(p01 * p23);
    float r01 = rr * p23, r23 = rr * p01;
    tc[0] = 2.0f * (r01 * d1) - 1.0f;
    tc[1] = 2.0f * (r01 * d0) - 1.0f;
    tc[2] = 2.0f * (r23 * d3) - 1.0f;
    tc[3] = 2.0f * (r23 * d2) - 1.0f;
    bf16x4 hv;
    hv[0] = (bf16_t)(so[0] * tc[0]);
    hv[1] = (bf16_t)(so[1] * tc[1]);
    hv[2] = (bf16_t)(so[2] * tc[2]);
    hv[3] = (bf16_t)(so[3] * tc[3]);
    return hv;
}

// ============== prep: fp32 -> bf16 bulk convert ==============
__global__ __launch_bounds__(256) void cvt_bf16_kernel(
    const float* __restrict__ src, bf16_t* __restrict__ dst, int n8)
{
    int i = blockIdx.x * 256 + threadIdx.x;
    if (i < n8) *(bf16x8*)(dst + (size_t)i * 8) = load8f(src + (size_t)i * 8);
}

// weights: scale by log2e (2*log2e for g-gate rows) BEFORE the single bf16
// rounding -> same rounding-error magnitude as unscaled conversion.
__global__ __launch_bounds__(256) void cvt_w_kernel(
    const float* __restrict__ src, bf16_t* __restrict__ dst, int n8)
{
    int i = blockIdx.x * 256 + threadIdx.x;
    if (i >= n8) return;
    int row  = (i >> 3) & 255;           // 8 elems never cross a row (64 % 8 == 0)
    int gate = row >> 6;
    float sc = (gate == 2) ? 2.885390082f : 1.442695041f;
    const float* p = src + (size_t)i * 8;
    f32x4 a = *(const f32x4*)p;
    f32x4 b = *(const f32x4*)(p + 4);
    bf16x8 r;
    r[0] = (bf16_t)(a[0]*sc); r[1] = (bf16_t)(a[1]*sc);
    r[2] = (bf16_t)(a[2]*sc); r[3] = (bf16_t)(a[3]*sc);
    r[4] = (bf16_t)(b[0]*sc); r[5] = (bf16_t)(b[1]*sc);
    r[6] = (bf16_t)(b[2]*sc); r[7] = (bf16_t)(b[3]*sc);
    *(bf16x8*)(dst + (size_t)i * 8) = r;
}

// ====== kernel 1: per-(tile,head) 2-layer LSTM, layer-split waves ======
// 512 threads: waves 0-3 layer0, waves 4-7 layer1, pipelined l0[t] || l1[t-1].
// NO global memory ops inside the t-loop: h1 history in LDS, bulk-stored
// after the final barrier.
template<bool PREP>
__global__ __launch_bounds__(512, 4) void lstm_pipe_kernel(
    const float* __restrict__ xg,   // (T, N, 64) fp32
    const bf16_t* __restrict__ xbf, // (T, N, 64) bf16 (PREP)
    const float* __restrict__ Wih,  // (2, 8, 256, 64)
    const float* __restrict__ Whh,  // (2, 8, 256, 64)
    const bf16_t* __restrict__ wbf, // [Wih | Whh] bf16, pre-scaled (PREP)
    const float* __restrict__ bih,  // (2, 8, 256)
    const float* __restrict__ bhh,  // (2, 8, 256)
    const float* __restrict__ h0g,  // (8, 2, N, 64)
    const float* __restrict__ c0g,  // (8, 2, N, 64)
    bf16_t* __restrict__ hsw)       // (96, N, 64) channel-major hs
{
    __shared__ __align__(16) bf16_t xT[T_LEN][MT][LDSP];       // x tile (27.6KB)
    __shared__ __align__(16) bf16_t h0A[2][MT][LDSP];          // layer0 h dbuf (4.6KB)
    __shared__ __align__(16) bf16_t h1H[T_LEN + 1][MT][LDSP];  // layer1 h history (30KB)
    __shared__ __align__(16) float  biasLds[2][4][4][16];      // [layer][wq][gate][gc]

    const int tid  = threadIdx.x;
    const int w    = tid >> 6;
    const int lane = tid & 63;
    const int quad = lane >> 4;
    const int col  = lane & 15;
    const int lw   = w >> 2;        // layer this wave serves
    const int wq   = w & 3;         // gate n-tile group within the layer
    const int a    = blockIdx.x & (NHEADS - 1);
    const int nb   = (blockIdx.x >> 3) * MT;

    // ---- x tile -> LDS ----
    #pragma unroll
    for (int it = 0; it < 3; ++it) {
        int e    = (it * 512 + tid) * 8;
        int t    = e >> 10;
        int node = (e >> 6) & (MT - 1);
        int f    = e & (HD - 1);
        bf16x8 v;
        if (PREP) v = *(const bf16x8*)(xbf + ((size_t)t * NNODES + nb + node) * HD + f);
        else      v = load8f(xg + ((size_t)t * NNODES + nb + node) * HD + f);
        *(bf16x8*)&xT[t][node][f] = v;
    }
    // ---- h0 init: layer0 -> h0A[0], layer1 -> h1H[0] ----
    {
        int e    = tid * 4;
        int l    = e >> 10;
        int node = (e >> 6) & (MT - 1);
        int hh   = e & (HD - 1);
        bf16x4 v = load4f(h0g + (((size_t)a * 2 + l) * NNODES + nb + node) * HD + hh);
        if (l == 0) *(bf16x4*)&h0A[0][node][hh] = v;
        else        *(bf16x4*)&h1H[0][node][hh] = v;
    }
    // ---- bias -> LDS (scaled to exp2 domain for PREP) ----
    {
        int l   = tid >> 8;
        int r   = tid & 255;
        int wqi = r >> 6;
        int nii = (r >> 4) & 3;
        int gc  = r & 15;
        int off = (l * NHEADS + a) * 256 + nii * 64 + wqi * 16 + gc;
        float sc = PREP ? (nii == 2 ? 2.885390082f : 1.442695041f) : 1.0f;
        biasLds[l][wqi][nii][gc] = (bih[off] + bhh[off]) * sc;
    }

    // ---- this wave's layer weights, register-resident ----
    bf16x8 wA[4][2], wB[4][2];      // [gate i/f/g/o][kfrag]; A=W_ih, B=W_hh
    #pragma unroll
    for (int ni = 0; ni < 4; ++ni)
        #pragma unroll
        for (int kf = 0; kf < 2; ++kf) {
            size_t off = (((size_t)lw * NHEADS + a) * 256 + (4 * ni + wq) * 16 + col) * HD
                       + kf * 32 + quad * 8;
            if (PREP) {
                wA[ni][kf] = *(const bf16x8*)(wbf + off);
                wB[ni][kf] = *(const bf16x8*)(wbf + WIH_ELEMS + off);
            } else {
                wA[ni][kf] = load8f(Wih + off);
                wB[ni][kf] = load8f(Whh + off);
            }
        }
    // cell state for (node=col, hcol = wq*16 + quad*4 + r)
    float creg[4];
    {
        f32x4 cv = *(const f32x4*)(c0g + (((size_t)a * 2 + lw) * NNODES + nb + col) * HD
                                   + wq * 16 + quad * 4);
        creg[0] = cv[0]; creg[1] = cv[1]; creg[2] = cv[2]; creg[3] = cv[3];
    }
    __syncthreads();

    int cur = 0;
    #pragma unroll 1
    for (int p = 0; p <= T_LEN; ++p) {
        const bool active = lw ? (p >= 1) : (p < T_LEN);
        if (active) {
            // l0: gates = Wih0*x[p]^T      + Whh0*h_l0[p-1]^T
            // l1: gates = Wih1*h_l0[p-1]^T + Whh1*h_l1[p-2]^T
            const bf16_t* P = lw ? &h0A[cur][0][0]     : &xT[p][0][0];
            const bf16_t* Q = lw ? &h1H[p - 1][0][0]   : &h0A[cur][0][0];
            bf16_t*       D = lw ? &h1H[p][0][0]       : &h0A[cur ^ 1][0][0];
            const int ro = col * LDSP + quad * 8;
            bf16x8 a0 = *(const bf16x8*)(P + ro);
            bf16x8 b0 = *(const bf16x8*)(Q + ro);
            f32x4 acc[4];
            #pragma unroll
            for (int ni = 0; ni < 4; ++ni) {
                f32x4 z = *(const f32x4*)&biasLds[lw][wq][ni][quad * 4];  // broadcast
                z = MFMA16(wA[ni][0], a0, z);
                acc[ni] = MFMA16(wB[ni][0], b0, z);
            }
            bf16x8 a1 = *(const bf16x8*)(P + ro + 32);
            bf16x8 b1 = *(const bf16x8*)(Q + ro + 32);
            #pragma unroll
            for (int ni = 0; ni < 4; ++ni) {
                f32x4 z = MFMA16(wA[ni][1], a1, acc[ni]);
                acc[ni] = MFMA16(wB[ni][1], b1, z);
            }
            bf16x4 hv = lstm_pointwise_sw<PREP>(acc, creg);
            *(bf16x4*)(D + col * LDSP + wq * 16 + quad * 4) = hv;   // one b64 write
        }
        __syncthreads();
        cur ^= 1;
    }

    // ---- epilogue: bulk hs store (12 x 2KB contiguous segments) ----
    #pragma unroll
    for (int it = 0; it < 3; ++it) {
        int i    = it * 512 + tid;           // 0 .. 1535
        int t    = i >> 7;                   // 12 timesteps
        int c    = i & 127;
        int node = c >> 3;
        int h8   = (c & 7) * 8;
        *(bf16x8*)(hsw + ((size_t)(a * T_LEN + t) * NNODES + nb + node) * HD + h8) =
            *(const bf16x8*)&h1H[t + 1][node][h8];
    }
}

// ================= kernel 2: 96 -> 12 channel mix =================
__global__ __launch_bounds__(256) void conv_reduce_kernel(
    const bf16_t* __restrict__ hsw,  // (96, N, 64)
    const float* __restrict__ cwg,   // (12, 96)
    const float* __restrict__ cbg,   // (12)
    float* __restrict__ outg)        // (12, N, 64)
{
    int flat = blockIdx.x * 256 + threadIdx.x;   // N*16 threads
    int n  = flat >> 4;
    int h4 = (flat & 15) * 4;
    f32x4 acc[T_LEN];
    #pragma unroll
    for (int o = 0; o < T_LEN; ++o) {
        float b = cbg[o];
        acc[o][0] = b; acc[o][1] = b; acc[o][2] = b; acc[o][3] = b;
    }
    const bf16_t* src = hsw + (size_t)n * HD + h4;
    #pragma unroll 6
    for (int c = 0; c < NHEADS * T_LEN; ++c) {
        bf16x4 hv = *(const bf16x4*)(src + (size_t)c * NNODES * HD);
        float h0 = (float)hv[0], h1 = (float)hv[1], h2 = (float)hv[2], h3 = (float)hv[3];
        #pragma unroll
        for (int o = 0; o < T_LEN; ++o) {
            float cv = cwg[o * (NHEADS * T_LEN) + c];
            acc[o][0] += cv * h0; acc[o][1] += cv * h1;
            acc[o][2] += cv * h2; acc[o][3] += cv * h3;
        }
    }
    #pragma unroll
    for (int o = 0; o < T_LEN; ++o)
        *(f32x4*)(outg + ((size_t)o * NNODES + n) * HD + h4) = acc[o];
}

// ============ fallback: R2's proven monolithic kernel (fp32 I/O) ============
struct SmemT {
    __align__(16) bf16_t xT[T_LEN][MT][LDSP];
    __align__(16) bf16_t hA[2][2][MT][LDSP];
    __align__(16) float  cwf[T_LEN][NHEADS * T_LEN];
    __align__(16) float  cbf[T_LEN];
};

__global__ __launch_bounds__(256) void lstm_mono_kernel(
    const float* __restrict__ xg, const float* __restrict__ Wih,
    const float* __restrict__ Whh, const float* __restrict__ bih,
    const float* __restrict__ bhh, const float* __restrict__ h0g,
    const float* __restrict__ c0g, const float* __restrict__ cwg,
    const float* __restrict__ cbg, float* __restrict__ outg)
{
    __shared__ SmemT s;
    const int tid  = threadIdx.x;
    const int w    = tid >> 6;
    const int lane = tid & 63;
    const int quad = lane >> 4;
    const int col  = lane & 15;
    const int nb   = blockIdx.x * MT;

    #pragma unroll
    for (int it = 0; it < 6; ++it) {
        int ci   = it * 256 + tid;
        int e    = ci * 8;
        int t    = e >> 10;
        int node = (e >> 6) & (MT - 1);
        int f    = e & (HD - 1);
        *(bf16x8*)&s.xT[t][node][f] =
            load8f(xg + ((size_t)t * NNODES + nb + node) * HD + f);
    }
    for (int i = tid; i < T_LEN * NHEADS * T_LEN; i += 256)
        s.cwf[i / 96][i % 96] = cwg[i];
    if (tid < T_LEN) s.cbf[tid] = cbg[tid];

    float conv_acc[T_LEN][4];
    #pragma unroll
    for (int o = 0; o < T_LEN; ++o)
        #pragma unroll
        for (int r = 0; r < 4; ++r) conv_acc[o][r] = 0.0f;

    #pragma unroll 1
    for (int a = 0; a < NHEADS; ++a) {
        bf16x8 wih[2][4][2], whh[2][4][2];
        #pragma unroll
        for (int l = 0; l < 2; ++l)
            #pragma unroll
            for (int ni = 0; ni < 4; ++ni)
                #pragma unroll
                for (int kf = 0; kf < 2; ++kf) {
                    size_t off = (((size_t)l * NHEADS + a) * 256 + (4 * ni + w) * 16 + col) * HD
                               + kf * 32 + quad * 8;
                    wih[l][ni][kf] = load8f(Wih + off);
                    whh[l][ni][kf] = load8f(Whh + off);
                }
        float bias[2][4];
        #pragma unroll
        for (int l = 0; l < 2; ++l)
            #pragma unroll
            for (int ni = 0; ni < 4; ++ni) {
                int off = (l * NHEADS + a) * 256 + ni * 64 + w * 16 + col;
                bias[l][ni] = bih[off] + bhh[off];
            }
        float creg[2][4];
        #pragma unroll
        for (int l = 0; l < 2; ++l)
            #pragma unroll
            for (int r = 0; r < 4; ++r)
                creg[l][r] = c0g[(((size_t)a * 2 + l) * NNODES + nb + quad * 4 + r) * HD
                                 + w * 16 + col];
        {
            int e    = tid * 8;
            int l    = e >> 10;
            int node = (e >> 6) & (MT - 1);
            int hh   = e & (HD - 1);
            *(bf16x8*)&s.hA[l][0][node][hh] =
                load8f(h0g + (((size_t)a * 2 + l) * NNODES + nb + node) * HD + hh);
        }
        __syncthreads();

        int cur = 0;
        #pragma unroll 1
        for (int t = 0; t < T_LEN; ++t) {
            bf16x8 xa0 = *(const bf16x8*)&s.xT[t][col][quad * 8];
            bf16x8 xa1 = *(const bf16x8*)&s.xT[t][col][32 + quad * 8];
            bf16x8 ha0 = *(const bf16x8*)&s.hA[0][cur][col][quad * 8];
            bf16x8 ha1 = *(const bf16x8*)&s.hA[0][cur][col][32 + quad * 8];
            f32x4 acc[4];
            #pragma unroll
            for (int ni = 0; ni < 4; ++ni) {
                f32x4 z = {0.f, 0.f, 0.f, 0.f};
                z = MFMA16(xa0, wih[0][ni][0], z);
                z = MFMA16(xa1, wih[0][ni][1], z);
                z = MFMA16(ha0, whh[0][ni][0], z);
                z = MFMA16(ha1, whh[0][ni][1], z);
                acc[ni] = z;
            }
            #pragma unroll
            for (int r = 0; r < 4; ++r) {
                float ig = fast_sigmoid(acc[0][r] + bias[0][0]);
                float fg = fast_sigmoid(acc[1][r] + bias[0][1]);
                float gg = fast_tanh   (acc[2][r] + bias[0][2]);
                float og = fast_sigmoid(acc[3][r] + bias[0][3]);
                float cn = fg * creg[0][r] + ig * gg;
                creg[0][r] = cn;
                s.hA[0][cur ^ 1][quad * 4 + r][w * 16 + col] = (bf16_t)(og * fast_tanh(cn));
            }
            __syncthreads();
            bf16x8 pa0 = *(const bf16x8*)&s.hA[0][cur ^ 1][col][quad * 8];
            bf16x8 pa1 = *(const bf16x8*)&s.hA[0][cur ^ 1][col][32 + quad * 8];
            bf16x8 qa0 = *(const bf16x8*)&s.hA[1][cur][col][quad * 8];
            bf16x8 qa1 = *(const bf16x8*)&s.hA[1][cur][col][32 + quad * 8];
            #pragma unroll
            for (int ni = 0; ni < 4; ++ni) {
                f32x4 z = {0.f, 0.f, 0.f, 0.f};
                z = MFMA16(pa0, wih[1][ni][0], z);
                z = MFMA16(pa1, wih[1][ni][1], z);
                z = MFMA16(qa0, whh[1][ni][0], z);
                z = MFMA16(qa1, whh[1][ni][1], z);
                acc[ni] = z;
            }
            float hn[4];
            #pragma unroll
            for (int r = 0; r < 4; ++r) {
                float ig = fast_sigmoid(acc[0][r] + bias[1][0]);
                float fg = fast_sigmoid(acc[1][r] + bias[1][1]);
                float gg = fast_tanh   (acc[2][r] + bias[1][2]);
                float og = fast_sigmoid(acc[3][r] + bias[1][3]);
                float cn = fg * creg[1][r] + ig * gg;
                creg[1][r] = cn;
                hn[r] = og * fast_tanh(cn);
                s.hA[1][cur ^ 1][quad * 4 + r][w * 16 + col] = (bf16_t)hn[r];
            }
            #pragma unroll
            for (int o = 0; o < T_LEN; ++o) {
                float cv = s.cwf[o][a * T_LEN + t];
                #pragma unroll
                for (int r = 0; r < 4; ++r) conv_acc[o][r] += cv * hn[r];
            }
            __syncthreads();
            cur ^= 1;
        }
    }
    #pragma unroll
    for (int o = 0; o < T_LEN; ++o)
        #pragma unroll
        for (int r = 0; r < 4; ++r)
            outg[((size_t)o * NNODES + nb + quad * 4 + r) * HD + w * 16 + col] =
                conv_acc[o][r] + s.cbf[o];
}

extern "C" void kernel_launch(void* const* d_in, const int* in_sizes, int n_in,
                              void* d_out, int out_size, void* d_ws, size_t ws_size,
                              hipStream_t stream) {
    (void)in_sizes; (void)n_in; (void)out_size;
    const float* x   = (const float*)d_in[0];
    const float* Wih = (const float*)d_in[1];
    const float* Whh = (const float*)d_in[2];
    const float* bih = (const float*)d_in[3];
    const float* bhh = (const float*)d_in[4];
    const float* h0  = (const float*)d_in[5];
    const float* c0  = (const float*)d_in[6];
    const float* cw  = (const float*)d_in[7];
    const float* cb  = (const float*)d_in[8];
    const size_t hs_bytes = (size_t)NHEADS * T_LEN * NNODES * HD * sizeof(bf16_t);
    const size_t x_bytes  = (size_t)T_LEN * NNODES * HD * sizeof(bf16_t);
    const size_t w_bytes  = (size_t)2 * WIH_ELEMS * sizeof(bf16_t);
    if (ws_size >= hs_bytes + x_bytes + w_bytes) {
        bf16_t* hs  = (bf16_t*)d_ws;
        bf16_t* xbf = (bf16_t*)((char*)d_ws + hs_bytes);
        bf16_t* wbf = (bf16_t*)((char*)d_ws + hs_bytes + x_bytes);
        const int n8x = T_LEN * NNODES * HD / 8;
        const int n8w = WIH_ELEMS / 8;
        cvt_bf16_kernel<<<dim3(n8x / 256), dim3(256), 0, stream>>>(x, xbf, n8x);
        cvt_w_kernel<<<dim3((n8w + 255) / 256), dim3(256), 0, stream>>>(Wih, wbf, n8w);
        cvt_w_kernel<<<dim3((n8w + 255) / 256), dim3(256), 0, stream>>>(Whh, wbf + WIH_ELEMS, n8w);
        lstm_pipe_kernel<true><<<dim3((NNODES / MT) * NHEADS), dim3(512), 0, stream>>>(
            x, xbf, Wih, Whh, wbf, bih, bhh, h0, c0, hs);
        conv_reduce_kernel<<<dim3(NNODES * 16 / 256), dim3(256), 0, stream>>>(
            hs, cw, cb, (float*)d_out);
    } else if (ws_size >= hs_bytes) {
        bf16_t* hs = (bf16_t*)d_ws;
        lstm_pipe_kernel<false><<<dim3((NNODES / MT) * NHEADS), dim3(512), 0, stream>>>(
            x, nullptr, Wih, Whh, nullptr, bih, bhh, h0, c0, hs);
        conv_reduce_kernel<<<dim3(NNODES * 16 / 256), dim3(256), 0, stream>>>(
            hs, cw, cb, (float*)d_out);
    } else {
        lstm_mono_kernel<<<dim3(NNODES / MT), dim3(256), 0, stream>>>(
            x, Wih, Whh, bih, bhh, h0, c0, cw, cb, (float*)d_out);
    }
}